// Round 8
// baseline (324.205 us; speedup 1.0000x reference)
//
#include <hip/hip_runtime.h>
#include <cmath>

// Problem constants (from reference)
constexpr int kN    = 3072;
constexpr int kR    = 7;
constexpr int kSPC  = 5;      // SPACE = R - ATTN_R
constexpr int kD    = 64;
constexpr int kWIN  = 128;
constexpr int kTOPK = 16;
constexpr int kE    = kN * 16;       // 49152 edges
constexpr int kRN   = kR * kN;       // 21504 (new_edge_list row width)
constexpr int kRD   = kR * kD;       // 448   (msg2 row width)
constexpr int kAW   = 2 * kWIN + 1;  // 257 (attention window width)
constexpr float kEPS = 1e-5f;

constexpr size_t kNelF = (size_t)kN * kRN;   // 66,060,288 floats (264 MB)
constexpr int kCapJ = 96;   // max edges per out-node bucket (mean 16; 12+ sigma safe)
constexpr int kCapI = 32;   // max attn edges per (k,i) bucket (mean 2.3)

__device__ __forceinline__ float wred_max(float v) {
#pragma unroll
  for (int off = 32; off; off >>= 1) v = fmaxf(v, __shfl_xor(v, off));
  return v;
}
__device__ __forceinline__ float wred_sum(float v) {
#pragma unroll
  for (int off = 32; off; off >>= 1) v += __shfl_xor(v, off);
  return v;
}

// ---------------------------------------------------------------------------
// 0) Zero the tiny stateful arrays: cntJ (3072), cntI (6144), gf (64).
__global__ __launch_bounds__(256) void k_zero_misc(int* __restrict__ cnts,
                                                   float* __restrict__ gf) {
  const int i = blockIdx.x * 256 + threadIdx.x;
  if (i < kN + 2 * kN) cnts[i] = 0;
  if (blockIdx.x == 0 && threadIdx.x < 64) gf[threadIdx.x] = 0.f;
}

// ---------------------------------------------------------------------------
// 1) Bucket edges: by out-node j (all relations) and by (k, in-node) for the
//    two attention relations. Small atomics (49K), replaces the 3.1M+8.6M
//    fp32 value-atomics of the old scatter path.
__global__ __launch_bounds__(256) void k_bucket(
    const int* __restrict__ nin, const int* __restrict__ nout,
    const int* __restrict__ rel, int* __restrict__ cntJ, int* __restrict__ cntI,
    int* __restrict__ bucketJ, int* __restrict__ bucketI) {
  const int e = blockIdx.x * 256 + threadIdx.x;
  if (e >= kE) return;
  const int j = nout[e], r = rel[e];
  int p = atomicAdd(&cntJ[j], 1);
  if (p < kCapJ) bucketJ[j * kCapJ + p] = e;
  if (r >= kSPC) {
    const int key = (r - kSPC) * kN + nin[e];
    int q = atomicAdd(&cntI[key], 1);
    if (q < kCapI) bucketI[key * kCapI + q] = e;
  }
}

// ---------------------------------------------------------------------------
// 2) Gather per out-node j: msg2 space blocks (r+2) and msgA (attn input).
//    One wave per j, lane = feature d. Fully writes msg2[.,128:448] and msgA.
__global__ __launch_bounds__(256) void k_gatherJ(
    const float* __restrict__ x, const float* __restrict__ ew,
    const int* __restrict__ nin, const int* __restrict__ rel,
    const int* __restrict__ cntJ, const int* __restrict__ bucketJ,
    float* __restrict__ msg2, float* __restrict__ msgA) {
  const int j = blockIdx.x * 4 + (threadIdx.x >> 6);
  const int lane = threadIdx.x & 63;
  int cnt = cntJ[j]; if (cnt > kCapJ) cnt = kCapJ;
  float a0 = 0.f, a1 = 0.f, a2 = 0.f, a3 = 0.f, a4 = 0.f, b0 = 0.f, b1 = 0.f;
  for (int t = 0; t < cnt; ++t) {
    const int e = bucketJ[j * kCapJ + t];
    const int i = nin[e], r = rel[e];
    const float v = ew[e] * x[i * kD + lane];
    if      (r == 0) a0 += v;
    else if (r == 1) a1 += v;
    else if (r == 2) a2 += v;
    else if (r == 3) a3 += v;
    else if (r == 4) a4 += v;
    else if (r == 5) b0 += v;
    else             b1 += v;
  }
  float* row = msg2 + (size_t)j * kRD;
  row[2 * kD + lane] = a0;
  row[3 * kD + lane] = a1;
  row[4 * kD + lane] = a2;
  row[5 * kD + lane] = a3;
  row[6 * kD + lane] = a4;
  msgA[(size_t)j * kD + lane] = b0;
  msgA[(size_t)(kN + j) * kD + lane] = b1;
}

// ---------------------------------------------------------------------------
// 3) Build Awin densely per (k,i) row (fully written; no memset, no atomics).
__global__ __launch_bounds__(256) void k_awin_build(
    const float* __restrict__ ew, const int* __restrict__ nout,
    const int* __restrict__ cntI, const int* __restrict__ bucketI,
    float* __restrict__ awin) {
  const int idx = blockIdx.x * 4 + (threadIdx.x >> 6);   // k*N + i
  const int lane = threadIdx.x & 63;
  const int i = idx % kN;
  int cnt = cntI[idx]; if (cnt > kCapI) cnt = kCapI;
  float c0 = 0.f, c1 = 0.f, c2 = 0.f, c3 = 0.f, c4 = 0.f;
  for (int t = 0; t < cnt; ++t) {
    const int e = bucketI[idx * kCapI + t];
    const int slot = nout[e] - i + kWIN;
    if (slot >= 0 && slot < kAW) {
      const float add = (lane == (slot & 63)) ? ew[e] : 0.f;
      const int s = slot >> 6;
      if      (s == 0) c0 += add;
      else if (s == 1) c1 += add;
      else if (s == 2) c2 += add;
      else if (s == 3) c3 += add;
      else             c4 += add;
    }
  }
  float* row = awin + (size_t)idx * kAW;
  row[lane] = c0;
  row[64 + lane] = c1;
  row[128 + lane] = c2;
  row[192 + lane] = c3;
  if (lane == 0) row[256] = c4;
}

// ---------------------------------------------------------------------------
// 4) h1[k,n,e] = msgA[k,n,:]·W_rel_s[5+k,:,e] + x[n,:]·W_self_s[:,e] + b_s[e]
__global__ __launch_bounds__(256) void k_h1(
    const float* __restrict__ x, const float* __restrict__ msgA,
    const float* __restrict__ Wrel, const float* __restrict__ Wself,
    const float* __restrict__ bs, float* __restrict__ h1) {
  const int k = blockIdx.y;
  const int e = threadIdx.x & 63;
  const int rl = threadIdx.x >> 6;
  const int n = blockIdx.x * 4 + rl;
  __shared__ float a[4][kD], xx[4][kD];
  a[rl][e] = msgA[(size_t)(k * kN + n) * kD + e];
  xx[rl][e] = x[n * kD + e];
  __syncthreads();
  const float* Wr = Wrel + (size_t)(kSPC + k) * kD * kD;
  float acc = bs[e];
#pragma unroll 8
  for (int d = 0; d < kD; ++d)
    acc += a[rl][d] * Wr[d * kD + e] + xx[rl][d] * Wself[d * kD + e];
  h1[(size_t)(k * kN + n) * kD + e] = acc;
}

// ---------------------------------------------------------------------------
// 5) Column batch-norm stats.
__global__ __launch_bounds__(256) void k_bnstats(
    const float* __restrict__ h, float* __restrict__ mean, float* __restrict__ inv) {
  const int c = blockIdx.x;
  const int mat = c >> 6, e = c & 63;
  const float* p = h + (size_t)mat * kN * kD + e;
  float s = 0.f, s2 = 0.f;
  for (int n = threadIdx.x; n < kN; n += 256) {
    float v = p[(size_t)n * kD];
    s += v; s2 += v * v;
  }
  __shared__ float sh0[256], sh1[256];
  sh0[threadIdx.x] = s; sh1[threadIdx.x] = s2;
  __syncthreads();
  for (int off = 128; off > 0; off >>= 1) {
    if (threadIdx.x < off) { sh0[threadIdx.x] += sh0[threadIdx.x + off]; sh1[threadIdx.x] += sh1[threadIdx.x + off]; }
    __syncthreads();
  }
  if (threadIdx.x == 0) {
    float m = sh0[0] / (float)kN;
    float var = sh1[0] / (float)kN - m * m;
    mean[c] = m;
    inv[c] = rsqrtf(var + kEPS);
  }
}

// ---------------------------------------------------------------------------
// 6) attn_in = relu(BN(h1)); q = attn_in @ Wq[k], kk = attn_in @ Wk[k]
__global__ __launch_bounds__(256) void k_qk(
    const float* __restrict__ h1, const float* __restrict__ mean,
    const float* __restrict__ inv, const float* __restrict__ Wq,
    const float* __restrict__ Wk, float* __restrict__ qb, float* __restrict__ kb) {
  const int k = blockIdx.y;
  const int e = threadIdx.x & 63;
  const int rl = threadIdx.x >> 6;
  const int n = blockIdx.x * 4 + rl;
  __shared__ float a[4][kD];
  float v = h1[(size_t)(k * kN + n) * kD + e];
  v = (v - mean[k * 64 + e]) * inv[k * 64 + e];
  a[rl][e] = v > 0.f ? v : 0.f;
  __syncthreads();
  const float* wq = Wq + (size_t)k * kD * kD;
  const float* wk = Wk + (size_t)k * kD * kD;
  float aq = 0.f, ak = 0.f;
#pragma unroll 8
  for (int d = 0; d < kD; ++d) {
    float av = a[rl][d];
    aq += av * wq[d * kD + e];
    ak += av * wk[d * kD + e];
  }
  qb[(size_t)(k * kN + n) * kD + e] = aq;
  kb[(size_t)(k * kN + n) * kD + e] = ak;
}

// ---------------------------------------------------------------------------
// 7) Attention: one wave per (k, n) row. NO scatter — patches eff = max(A,S)
//    into awin at selected cells and records {col,val} lists for the NEL pass.
__global__ __launch_bounds__(256) void k_attn(
    const float* __restrict__ qb, const float* __restrict__ kb,
    float* __restrict__ awin, int* __restrict__ selCols,
    float* __restrict__ selVals, int* __restrict__ selCnt) {
  const int lane = threadIdx.x & 63;
  const int w = threadIdx.x >> 6;
  const int idx = blockIdx.x * 4 + w;
  const int k = idx / kN;
  const int n = idx - k * kN;
  __shared__ float qs[4][kD];
  qs[w][lane] = qb[(size_t)(k * kN + n) * kD + lane];
  __syncthreads();
  const int lo = n - kWIN < 0 ? 0 : n - kWIN;
  const int hi = n + kWIN > kN - 1 ? kN - 1 : n + kWIN;

  // scores: sc[s][h] = (q[n,h,:]·k[m,h,:]) / sqrt(16) / TEMP = dot * 0.5
  float sc[5][4];
#pragma unroll
  for (int s = 0; s < 5; ++s) {
    const int m = lo + s * 64 + lane;
    if (m <= hi) {
      const float4* krow = reinterpret_cast<const float4*>(kb + (size_t)(k * kN + m) * kD);
#pragma unroll
      for (int h = 0; h < 4; ++h) {
        float acc = 0.f;
#pragma unroll
        for (int g = 0; g < 4; ++g) {
          float4 kv = krow[h * 4 + g];
          const float* qp = &qs[w][h * 16 + g * 4];
          acc += kv.x * qp[0] + kv.y * qp[1] + kv.z * qp[2] + kv.w * qp[3];
        }
        sc[s][h] = acc * 0.5f;
      }
    } else {
#pragma unroll
      for (int h = 0; h < 4; ++h) sc[s][h] = -3.0e38f;
    }
  }

  // per-head windowed softmax, head-mean
  float pm[5] = {0.f, 0.f, 0.f, 0.f, 0.f};
#pragma unroll
  for (int h = 0; h < 4; ++h) {
    float lm = fmaxf(fmaxf(fmaxf(sc[0][h], sc[1][h]), fmaxf(sc[2][h], sc[3][h])), sc[4][h]);
    float mx = wred_max(lm);
    float eh[5], den = 0.f;
#pragma unroll
    for (int s = 0; s < 5; ++s) {
      eh[s] = (sc[s][h] > -1.0e38f) ? expf(sc[s][h] - mx) : 0.f;
      den += eh[s];
    }
    den = wred_sum(den);
    float rdn = 1.f / den;
#pragma unroll
    for (int s = 0; s < 5; ++s) pm[s] += eh[s] * rdn;
  }
#pragma unroll
  for (int s = 0; s < 5; ++s) pm[s] *= 0.25f;

  // exact 16th largest: 16 rounds of remove-one-max (tie-exact)
  float rem[5];
#pragma unroll
  for (int s = 0; s < 5; ++s) {
    const int m = lo + s * 64 + lane;
    rem[s] = (m <= hi) ? pm[s] : -1.f;
  }
  float kth = 0.f;
  for (int t = 0; t < kTOPK; ++t) {
    float lm = fmaxf(fmaxf(fmaxf(rem[0], rem[1]), fmaxf(rem[2], rem[3])), rem[4]);
    float gm = wred_max(lm);
    unsigned long long b = __ballot(lm == gm);
    int src = __ffsll((unsigned long long)b) - 1;
    if (lane == src) {
      if (rem[0] == gm) rem[0] = -2.f;
      else if (rem[1] == gm) rem[1] = -2.f;
      else if (rem[2] == gm) rem[2] = -2.f;
      else if (rem[3] == gm) rem[3] = -2.f;
      else rem[4] = -2.f;
    }
    kth = gm;
  }

  // selection (probs >= kth, tie-inclusive), prefix positions
  bool sel[5];
  int cl = 0;
#pragma unroll
  for (int s = 0; s < 5; ++s) {
    const int m = lo + s * 64 + lane;
    sel[s] = (m <= hi) && (pm[s] >= kth);
    cl += sel[s] ? 1 : 0;
  }
  int v = cl;
#pragma unroll
  for (int off = 1; off < 64; off <<= 1) {
    int t = __shfl_up(v, off);
    if (lane >= off) v += t;
  }
  const int excl = v - cl;
  const int total = __shfl(v, 63);
  const int tot = total < 64 ? total : 64;
  const int rowbase = idx * 64;
  float* arow = awin + (size_t)idx * kAW;
  int p = excl;
#pragma unroll
  for (int s = 0; s < 5; ++s) {
    if (sel[s] && p < 64) {
      const int m = lo + s * 64 + lane;
      const float a = arow[m - n + kWIN];
      const float fin = fmaxf(a, pm[s]);   // B = max(A, S) at selected cells
      arow[m - n + kWIN] = fin;            // patch: awin becomes eff
      selCols[rowbase + p] = m;
      selVals[rowbase + p] = fin;
      ++p;
    }
  }
  if (lane == 0) selCnt[idx] = tot;
}

// ---------------------------------------------------------------------------
// 8) Gather attention contribution: msg2[m, k*64+d] = sum_n eff[n,m]*x[n,d].
//    eff[n,m] = awin[k][n][m-n+128] (A at unselected, max(A,S) at selected).
//    Uniform zero-skip: eff is lane-uniform; ~92% of window cells are zero.
__global__ __launch_bounds__(256) void k_gatherA(
    const float* __restrict__ awin, const float* __restrict__ x,
    float* __restrict__ msg2) {
  const int idx = blockIdx.x * 4 + (threadIdx.x >> 6);   // k*N + m
  const int lane = threadIdx.x & 63;
  const int k = idx / kN;
  const int m = idx - k * kN;
  const int nlo = m - kWIN < 0 ? 0 : m - kWIN;
  const int nhi = m + kWIN > kN - 1 ? kN - 1 : m + kWIN;
  float acc = 0.f;
  for (int n = nlo; n <= nhi; ++n) {
    const float eff = awin[(size_t)(k * kN + n) * kAW + (m - n + kWIN)];
    if (eff != 0.f) acc += eff * x[n * kD + lane];
  }
  msg2[(size_t)m * kRD + k * kD + lane] = acc;
}

// ---------------------------------------------------------------------------
// 9) Out-of-window attention edges: B = max(A, 0) = A there; add to msg2.
//    (~13K edges -> 0.8M lane-atomics; runs AFTER k_gatherA's overwrite.)
__global__ __launch_bounds__(256) void k_edgeOOW(
    const float* __restrict__ x, const float* __restrict__ ew,
    const int* __restrict__ nin, const int* __restrict__ nout,
    const int* __restrict__ rel, float* __restrict__ msg2) {
  const int e = blockIdx.x * 4 + (threadIdx.x >> 6);
  const int lane = threadIdx.x & 63;
  const int r = rel[e];
  if (r < kSPC) return;                       // wave-uniform
  const int i = nin[e], j = nout[e];
  int diff = i - j; if (diff < 0) diff = -diff;
  if (diff <= kWIN) return;                   // in-window handled by gather
  const int k = r - kSPC;
  atomicAdd(&msg2[(size_t)j * kRD + k * kD + lane], ew[e] * x[i * kD + lane]);
}

// ---------------------------------------------------------------------------
// 10) hidden pre-activation: hpre = msg2·W_msg + x·Wg + bg
__global__ __launch_bounds__(256) void k_hpre(
    const float* __restrict__ msg2, const float* __restrict__ x,
    const float* __restrict__ Wmsg, const float* __restrict__ Wg,
    const float* __restrict__ bg, float* __restrict__ hpre) {
  const int e = threadIdx.x & 63;
  const int rl = threadIdx.x >> 6;
  const int n0 = blockIdx.x * 4;
  __shared__ float ml[4][kRD];
  __shared__ float xl[4][kD];
  for (int idx = threadIdx.x; idx < 4 * kRD; idx += 256) {
    int rr = idx / kRD, c = idx - rr * kRD;
    ml[rr][c] = msg2[(size_t)(n0 + rr) * kRD + c];
  }
  {
    int rr = threadIdx.x >> 6, c = threadIdx.x & 63;
    xl[rr][c] = x[(n0 + rr) * kD + c];
  }
  __syncthreads();
  float acc = bg[e];
#pragma unroll 8
  for (int c = 0; c < kRD; ++c) acc += ml[rl][c] * Wmsg[c * kD + e];
#pragma unroll 8
  for (int d = 0; d < kD; ++d) acc += xl[rl][d] * Wg[d * kD + e];
  hpre[(size_t)(n0 + rl) * kD + e] = acc;
}

// ---------------------------------------------------------------------------
// 11) NEL value pass 1: per-edge atomicAdd of A into the zeroed NEL (49K).
__global__ __launch_bounds__(256) void k_nel_edges(
    const float* __restrict__ ew, const int* __restrict__ nin,
    const int* __restrict__ nout, const int* __restrict__ rel,
    float* __restrict__ nel) {
  const int e = blockIdx.x * 256 + threadIdx.x;
  if (e >= kE) return;
  const int r = rel[e], i = nin[e], j = nout[e];
  const int col = (r < kSPC) ? (r + 2) * kN + j : (r - kSPC) * kN + j;
  atomicAdd(&nel[(size_t)i * kRN + col], ew[e]);
}

// ---------------------------------------------------------------------------
// 12) NEL value pass 2: selected cells overwrite with fin = max(A, S).
__global__ __launch_bounds__(256) void k_nel_sel(
    const int* __restrict__ selCols, const float* __restrict__ selVals,
    const int* __restrict__ selCnt, float* __restrict__ nel) {
  const int idx = blockIdx.x * 4 + (threadIdx.x >> 6);
  const int lane = threadIdx.x & 63;
  const int k = idx / kN, n = idx - k * kN;
  const int cnt = selCnt[idx];
  if (lane < cnt) {
    const int m = selCols[idx * 64 + lane];
    nel[(size_t)n * kRN + (size_t)k * kN + m] = selVals[idx * 64 + lane];
  }
}

// ---------------------------------------------------------------------------
// 13) hidden = relu(BN(hpre)) in place; graph_feature += column sums
__global__ __launch_bounds__(256) void k_hfin(
    float* __restrict__ hid, const float* __restrict__ mean,
    const float* __restrict__ inv, float* __restrict__ gf) {
  const int e = threadIdx.x & 63;
  const int rl = threadIdx.x >> 6;
  const int n = blockIdx.x * 4 + rl;
  float v = hid[(size_t)n * kD + e];
  v = (v - mean[e]) * inv[e];
  v = v > 0.f ? v : 0.f;
  hid[(size_t)n * kD + e] = v;
  __shared__ float sh[4][kD];
  sh[rl][e] = v;
  __syncthreads();
  if (threadIdx.x < 64)
    atomicAdd(&gf[e], sh[0][e] + sh[1][e] + sh[2][e] + sh[3][e]);
}

// ---------------------------------------------------------------------------
extern "C" void kernel_launch(void* const* d_in, const int* in_sizes, int n_in,
                              void* d_out, int out_size, void* d_ws, size_t ws_size,
                              hipStream_t stream) {
  (void)in_sizes; (void)n_in; (void)ws_size; (void)out_size;
  const float* x     = (const float*)d_in[0];
  const float* ew    = (const float*)d_in[1];
  const float* Wrel  = (const float*)d_in[2];
  const float* Wself = (const float*)d_in[3];
  const float* bs    = (const float*)d_in[4];
  const float* Wq    = (const float*)d_in[5];
  const float* Wk    = (const float*)d_in[6];
  const float* Wmsg  = (const float*)d_in[7];
  const float* Wg    = (const float*)d_in[8];
  const float* bg    = (const float*)d_in[9];
  const int*   nin   = (const int*)d_in[10];
  const int*   nout  = (const int*)d_in[11];
  const int*   rel   = (const int*)d_in[12];

  float* gf  = (float*)d_out;                    // 64
  float* hid = gf + 64;                          // N*64 (fully written by k_hpre)
  float* nel = hid + (size_t)kN * kD;            // N*R*N (memset + value passes)

  float* w0     = (float*)d_ws;
  float* msg2   = w0;                                    // N*448 (fully written)
  float* msgA   = msg2 + (size_t)kN * kRD;               // 2*N*64 (fully written)
  float* awin   = msgA + (size_t)2 * kN * kD;            // 2*N*257 (fully written)
  float* h1     = awin + (size_t)2 * kN * kAW;           // 2*N*64
  float* qb     = h1   + (size_t)2 * kN * kD;            // 2*N*64
  float* kb     = qb   + (size_t)2 * kN * kD;            // 2*N*64
  float* mean1  = kb   + (size_t)2 * kN * kD;            // 128
  float* inv1   = mean1 + 128;                           // 128
  float* mean2  = inv1 + 128;                            // 64
  float* inv2   = mean2 + 64;                            // 64
  float* selVals= inv2 + 64;                             // 2*N*64
  int* selCols  = (int*)(selVals + (size_t)2 * kN * 64); // 2*N*64
  int* selCnt   = selCols + (size_t)2 * kN * 64;         // 2*N
  int* cnts     = selCnt + 2 * kN;                       // cntJ(3072) + cntI(6144)
  int* cntJ     = cnts;
  int* cntI     = cnts + kN;
  int* bucketJ  = cnts + 3 * kN;                         // 3072*96
  int* bucketI  = bucketJ + (size_t)kN * kCapJ;          // 6144*32

  // The 264 MB output zero (true in-graph cost ~80 us, R7-R6 delta; the
  // 155 us per-dispatch rocprof figures are a profiling artifact).
  hipMemsetAsync(nel, 0, kNelF * sizeof(float), stream);
  k_zero_misc<<<(3 * kN + 255) / 256, 256, 0, stream>>>(cnts, gf);
  k_bucket<<<(kE + 255) / 256, 256, 0, stream>>>(nin, nout, rel, cntJ, cntI, bucketJ, bucketI);
  k_gatherJ<<<kN / 4, 256, 0, stream>>>(x, ew, nin, rel, cntJ, bucketJ, msg2, msgA);
  k_awin_build<<<(2 * kN) / 4, 256, 0, stream>>>(ew, nout, cntI, bucketI, awin);
  dim3 g2(kN / 4, 2);
  k_h1<<<g2, 256, 0, stream>>>(x, msgA, Wrel, Wself, bs, h1);
  k_bnstats<<<128, 256, 0, stream>>>(h1, mean1, inv1);
  k_qk<<<g2, 256, 0, stream>>>(h1, mean1, inv1, Wq, Wk, qb, kb);
  k_attn<<<(2 * kN) / 4, 256, 0, stream>>>(qb, kb, awin, selCols, selVals, selCnt);
  k_gatherA<<<(2 * kN) / 4, 256, 0, stream>>>(awin, x, msg2);
  k_edgeOOW<<<kE / 4, 256, 0, stream>>>(x, ew, nin, nout, rel, msg2);
  k_hpre<<<kN / 4, 256, 0, stream>>>(msg2, x, Wmsg, Wg, bg, hid);
  k_bnstats<<<64, 256, 0, stream>>>(hid, mean2, inv2);
  k_nel_edges<<<(kE + 255) / 256, 256, 0, stream>>>(ew, nin, nout, rel, nel);
  k_nel_sel<<<(2 * kN) / 4, 256, 0, stream>>>(selCols, selVals, selCnt, nel);
  k_hfin<<<kN / 4, 256, 0, stream>>>(hid, mean2, inv2, gf);
}

// Round 9
// 237.778 us; speedup vs baseline: 1.3635x; 1.3635x over previous
//
#include <hip/hip_runtime.h>
#include <cmath>

// Problem constants (from reference)
constexpr int kN    = 3072;
constexpr int kR    = 7;
constexpr int kSPC  = 5;      // SPACE = R - ATTN_R
constexpr int kD    = 64;
constexpr int kWIN  = 128;
constexpr int kTOPK = 16;
constexpr int kE    = kN * 16;       // 49152 edges
constexpr int kRN   = kR * kN;       // 21504 (new_edge_list row width)
constexpr int kRD   = kR * kD;       // 448   (msg2 row width)
constexpr float kEPS = 1e-5f;

__device__ __forceinline__ float wred_max(float v) {
#pragma unroll
  for (int off = 32; off; off >>= 1) v = fmaxf(v, __shfl_xor(v, off));
  return v;
}
__device__ __forceinline__ float wred_sum(float v) {
#pragma unroll
  for (int off = 32; off; off >>= 1) v += __shfl_xor(v, off);
  return v;
}

// ---------------------------------------------------------------------------
// 1) Edge scatter: one wave per edge, lane = feature.
//    r < 5 : msg2[j, (r+2)*64 + d] += w * x[i,d];  NEL[i, (r+2)*N + j] += w
//    r >= 5: msgA[(r-5), j, d]     += w * x[i,d];  NEL[i, (r-5)*N + j] += w
__global__ __launch_bounds__(256) void k_scatter(
    const float* __restrict__ x, const float* __restrict__ ew,
    const int* __restrict__ nin, const int* __restrict__ nout,
    const int* __restrict__ rel,
    float* __restrict__ msg2, float* __restrict__ msgA, float* __restrict__ nel) {
  const int e = blockIdx.x * 4 + (threadIdx.x >> 6);
  const int lane = threadIdx.x & 63;
  const int r = rel[e], i = nin[e], j = nout[e];
  const float w = ew[e];
  const float v = w * x[i * kD + lane];
  if (r < kSPC) {
    atomicAdd(&msg2[(size_t)j * kRD + (r + 2) * kD + lane], v);
    if (lane == 0) atomicAdd(&nel[(size_t)i * kRN + (size_t)(r + 2) * kN + j], w);
  } else {
    const int k = r - kSPC;
    atomicAdd(&msgA[(size_t)(k * kN + j) * kD + lane], v);
    if (lane == 0) atomicAdd(&nel[(size_t)i * kRN + (size_t)k * kN + j], w);
  }
}

// ---------------------------------------------------------------------------
// 2) h1[k,n,e] = msgA[k,n,:]·W_rel_s[5+k,:,e] + x[n,:]·W_self_s[:,e] + b_s[e]
__global__ __launch_bounds__(256) void k_h1(
    const float* __restrict__ x, const float* __restrict__ msgA,
    const float* __restrict__ Wrel, const float* __restrict__ Wself,
    const float* __restrict__ bs, float* __restrict__ h1) {
  const int k = blockIdx.y;
  const int e = threadIdx.x & 63;
  const int rl = threadIdx.x >> 6;
  const int n = blockIdx.x * 4 + rl;
  __shared__ float a[4][kD], xx[4][kD];
  a[rl][e] = msgA[(size_t)(k * kN + n) * kD + e];
  xx[rl][e] = x[n * kD + e];
  __syncthreads();
  const float* Wr = Wrel + (size_t)(kSPC + k) * kD * kD;
  float acc = bs[e];
#pragma unroll 8
  for (int d = 0; d < kD; ++d)
    acc += a[rl][d] * Wr[d * kD + e] + xx[rl][d] * Wself[d * kD + e];
  h1[(size_t)(k * kN + n) * kD + e] = acc;
}

// ---------------------------------------------------------------------------
// 3) Column batch-norm stats: one block per column c = mat*64 + e over N rows.
__global__ __launch_bounds__(256) void k_bnstats(
    const float* __restrict__ h, float* __restrict__ mean, float* __restrict__ inv) {
  const int c = blockIdx.x;
  const int mat = c >> 6, e = c & 63;
  const float* p = h + (size_t)mat * kN * kD + e;
  float s = 0.f, s2 = 0.f;
  for (int n = threadIdx.x; n < kN; n += 256) {
    float v = p[(size_t)n * kD];
    s += v; s2 += v * v;
  }
  __shared__ float sh0[256], sh1[256];
  sh0[threadIdx.x] = s; sh1[threadIdx.x] = s2;
  __syncthreads();
  for (int off = 128; off > 0; off >>= 1) {
    if (threadIdx.x < off) { sh0[threadIdx.x] += sh0[threadIdx.x + off]; sh1[threadIdx.x] += sh1[threadIdx.x + off]; }
    __syncthreads();
  }
  if (threadIdx.x == 0) {
    float m = sh0[0] / (float)kN;
    float var = sh1[0] / (float)kN - m * m;
    mean[c] = m;
    inv[c] = rsqrtf(var + kEPS);
  }
}

// ---------------------------------------------------------------------------
// 4) attn_in = relu(BN(h1)); q = attn_in @ Wq[k], kk = attn_in @ Wk[k]
__global__ __launch_bounds__(256) void k_qk(
    const float* __restrict__ h1, const float* __restrict__ mean,
    const float* __restrict__ inv, const float* __restrict__ Wq,
    const float* __restrict__ Wk, float* __restrict__ qb, float* __restrict__ kb) {
  const int k = blockIdx.y;
  const int e = threadIdx.x & 63;
  const int rl = threadIdx.x >> 6;
  const int n = blockIdx.x * 4 + rl;
  __shared__ float a[4][kD];
  float v = h1[(size_t)(k * kN + n) * kD + e];
  v = (v - mean[k * 64 + e]) * inv[k * 64 + e];
  a[rl][e] = v > 0.f ? v : 0.f;
  __syncthreads();
  const float* wq = Wq + (size_t)k * kD * kD;
  const float* wk = Wk + (size_t)k * kD * kD;
  float aq = 0.f, ak = 0.f;
#pragma unroll 8
  for (int d = 0; d < kD; ++d) {
    float av = a[rl][d];
    aq += av * wq[d * kD + e];
    ak += av * wk[d * kD + e];
  }
  qb[(size_t)(k * kN + n) * kD + e] = aq;
  kb[(size_t)(k * kN + n) * kD + e] = ak;
}

// ---------------------------------------------------------------------------
// 5) Attention: one wave per (k, n) row. Windowed scores -> per-head softmax
//    -> head-mean probs -> exact 16th order statistic -> write max(A, p) into
//    NEL output cells, record selected columns, scatter into msg2 attn blocks.
__global__ __launch_bounds__(256) void k_attn(
    const float* __restrict__ qb, const float* __restrict__ kb,
    const float* __restrict__ x, float* __restrict__ nel,
    float* __restrict__ msg2, int* __restrict__ selCols, int* __restrict__ selCnt) {
  const int lane = threadIdx.x & 63;
  const int w = threadIdx.x >> 6;
  const int idx = blockIdx.x * 4 + w;
  const int k = idx / kN;
  const int n = idx - k * kN;
  __shared__ float qs[4][kD];
  __shared__ float sval[4][64];
  __shared__ int scol[4][64];
  qs[w][lane] = qb[(size_t)(k * kN + n) * kD + lane];
  __syncthreads();
  const int lo = n - kWIN < 0 ? 0 : n - kWIN;
  const int hi = n + kWIN > kN - 1 ? kN - 1 : n + kWIN;

  // scores: sc[s][h] = (q[n,h,:]·k[m,h,:]) / sqrt(16) / TEMP = dot * 0.5
  float sc[5][4];
#pragma unroll
  for (int s = 0; s < 5; ++s) {
    const int m = lo + s * 64 + lane;
    if (m <= hi) {
      const float4* krow = reinterpret_cast<const float4*>(kb + (size_t)(k * kN + m) * kD);
#pragma unroll
      for (int h = 0; h < 4; ++h) {
        float acc = 0.f;
#pragma unroll
        for (int g = 0; g < 4; ++g) {
          float4 kv = krow[h * 4 + g];
          const float* qp = &qs[w][h * 16 + g * 4];
          acc += kv.x * qp[0] + kv.y * qp[1] + kv.z * qp[2] + kv.w * qp[3];
        }
        sc[s][h] = acc * 0.5f;
      }
    } else {
#pragma unroll
      for (int h = 0; h < 4; ++h) sc[s][h] = -3.0e38f;
    }
  }

  // per-head windowed softmax, head-mean
  float pm[5] = {0.f, 0.f, 0.f, 0.f, 0.f};
#pragma unroll
  for (int h = 0; h < 4; ++h) {
    float lm = fmaxf(fmaxf(fmaxf(sc[0][h], sc[1][h]), fmaxf(sc[2][h], sc[3][h])), sc[4][h]);
    float mx = wred_max(lm);
    float eh[5], den = 0.f;
#pragma unroll
    for (int s = 0; s < 5; ++s) {
      eh[s] = (sc[s][h] > -1.0e38f) ? expf(sc[s][h] - mx) : 0.f;
      den += eh[s];
    }
    den = wred_sum(den);
    float rdn = 1.f / den;
#pragma unroll
    for (int s = 0; s < 5; ++s) pm[s] += eh[s] * rdn;
  }
#pragma unroll
  for (int s = 0; s < 5; ++s) pm[s] *= 0.25f;

  // exact 16th largest: 16 rounds of remove-one-max (tie-exact)
  float rem[5];
#pragma unroll
  for (int s = 0; s < 5; ++s) {
    const int m = lo + s * 64 + lane;
    rem[s] = (m <= hi) ? pm[s] : -1.f;
  }
  float kth = 0.f;
  for (int t = 0; t < kTOPK; ++t) {
    float lm = fmaxf(fmaxf(fmaxf(rem[0], rem[1]), fmaxf(rem[2], rem[3])), rem[4]);
    float gm = wred_max(lm);
    unsigned long long b = __ballot(lm == gm);
    int src = __ffsll((unsigned long long)b) - 1;
    if (lane == src) {
      if (rem[0] == gm) rem[0] = -2.f;
      else if (rem[1] == gm) rem[1] = -2.f;
      else if (rem[2] == gm) rem[2] = -2.f;
      else if (rem[3] == gm) rem[3] = -2.f;
      else rem[4] = -2.f;
    }
    kth = gm;
  }

  // selection (probs >= kth, tie-inclusive), prefix positions
  bool sel[5];
  int cl = 0;
#pragma unroll
  for (int s = 0; s < 5; ++s) {
    const int m = lo + s * 64 + lane;
    sel[s] = (m <= hi) && (pm[s] >= kth);
    cl += sel[s] ? 1 : 0;
  }
  int v = cl;
#pragma unroll
  for (int off = 1; off < 64; off <<= 1) {
    int t = __shfl_up(v, off);
    if (lane >= off) v += t;
  }
  const int excl = v - cl;
  const int total = __shfl(v, 63);
  const int tot = total < 64 ? total : 64;
  const int rowbase = (k * kN + n) * 64;
  int p = excl;
#pragma unroll
  for (int s = 0; s < 5; ++s) {
    if (sel[s] && p < 64) {
      const int m = lo + s * 64 + lane;
      const size_t cell = (size_t)n * kRN + (size_t)k * kN + m;
      float a = nel[cell];
      float fin = fmaxf(a, pm[s]);   // B = max(A, S) at selected cells
      nel[cell] = fin;
      scol[w][p] = m;
      sval[w][p] = fin;
      selCols[rowbase + p] = m;
      ++p;
    }
  }
  if (lane == 0) selCnt[k * kN + n] = tot;

  // scatter: msg2[m, k*64 + d] += fin * x[n, d]
  const float xv = x[n * kD + lane];
  for (int t = 0; t < tot; ++t) {
    const int m = scol[w][t];
    const float fv = sval[w][t];
    atomicAdd(&msg2[(size_t)m * kRD + k * kD + lane], fv * xv);
  }
}

// ---------------------------------------------------------------------------
// 6) Attention-relation edge fixup: cells NOT selected contribute A (= sum of
//    duplicate edge weights); selected cells were already fully counted.
__global__ __launch_bounds__(256) void k_edgefix(
    const float* __restrict__ x, const float* __restrict__ ew,
    const int* __restrict__ nin, const int* __restrict__ nout,
    const int* __restrict__ rel, const int* __restrict__ selCols,
    const int* __restrict__ selCnt, float* __restrict__ msg2) {
  const int e = blockIdx.x * 4 + (threadIdx.x >> 6);
  const int lane = threadIdx.x & 63;
  const int r = rel[e];
  if (r < kSPC) return;                       // wave-uniform
  const int k = r - kSPC, i = nin[e], j = nout[e];
  int diff = i - j; if (diff < 0) diff = -diff;
  if (diff <= kWIN) {
    const int cnt = selCnt[k * kN + i];
    bool mine = (lane < cnt) && (selCols[(k * kN + i) * 64 + lane] == j);
    if (__ballot(mine)) return;               // cell was selected -> skip
  }
  atomicAdd(&msg2[(size_t)j * kRD + k * kD + lane], ew[e] * x[i * kD + lane]);
}

// ---------------------------------------------------------------------------
// 7) hidden pre-activation: hpre[n,e] = msg2[n,:]·W_msg[:,e] + x[n,:]·Wg[:,e] + bg[e]
__global__ __launch_bounds__(256) void k_hpre(
    const float* __restrict__ msg2, const float* __restrict__ x,
    const float* __restrict__ Wmsg, const float* __restrict__ Wg,
    const float* __restrict__ bg, float* __restrict__ hpre) {
  const int e = threadIdx.x & 63;
  const int rl = threadIdx.x >> 6;
  const int n0 = blockIdx.x * 4;
  __shared__ float ml[4][kRD];
  __shared__ float xl[4][kD];
  for (int idx = threadIdx.x; idx < 4 * kRD; idx += 256) {
    int rr = idx / kRD, c = idx - rr * kRD;
    ml[rr][c] = msg2[(size_t)(n0 + rr) * kRD + c];
  }
  {
    int rr = threadIdx.x >> 6, c = threadIdx.x & 63;
    xl[rr][c] = x[(n0 + rr) * kD + c];
  }
  __syncthreads();
  float acc = bg[e];
#pragma unroll 8
  for (int c = 0; c < kRD; ++c) acc += ml[rl][c] * Wmsg[c * kD + e];
#pragma unroll 8
  for (int d = 0; d < kD; ++d) acc += xl[rl][d] * Wg[d * kD + e];
  hpre[(size_t)(n0 + rl) * kD + e] = acc;
}

// ---------------------------------------------------------------------------
// 8) hidden = relu(BN(hpre)) in place; graph_feature += column sums
__global__ __launch_bounds__(256) void k_hfin(
    float* __restrict__ hid, const float* __restrict__ mean,
    const float* __restrict__ inv, float* __restrict__ gf) {
  const int e = threadIdx.x & 63;
  const int rl = threadIdx.x >> 6;
  const int n = blockIdx.x * 4 + rl;
  float v = hid[(size_t)n * kD + e];
  v = (v - mean[e]) * inv[e];
  v = v > 0.f ? v : 0.f;
  hid[(size_t)n * kD + e] = v;
  __shared__ float sh[4][kD];
  sh[rl][e] = v;
  __syncthreads();
  if (threadIdx.x < 64)
    atomicAdd(&gf[e], sh[0][e] + sh[1][e] + sh[2][e] + sh[3][e]);
}

// ---------------------------------------------------------------------------
extern "C" void kernel_launch(void* const* d_in, const int* in_sizes, int n_in,
                              void* d_out, int out_size, void* d_ws, size_t ws_size,
                              hipStream_t stream) {
  (void)in_sizes; (void)n_in; (void)ws_size;
  const float* x     = (const float*)d_in[0];
  const float* ew    = (const float*)d_in[1];
  const float* Wrel  = (const float*)d_in[2];
  const float* Wself = (const float*)d_in[3];
  const float* bs    = (const float*)d_in[4];
  const float* Wq    = (const float*)d_in[5];
  const float* Wk    = (const float*)d_in[6];
  const float* Wmsg  = (const float*)d_in[7];
  const float* Wg    = (const float*)d_in[8];
  const float* bg    = (const float*)d_in[9];
  const int*   nin   = (const int*)d_in[10];
  const int*   nout  = (const int*)d_in[11];
  const int*   rel   = (const int*)d_in[12];

  float* gf  = (float*)d_out;                    // 64
  float* hid = gf + 64;                          // N*64
  float* nel = hid + (size_t)kN * kD;            // N * R*N

  float* w0    = (float*)d_ws;
  float* msg2  = w0;                             // N*448   (zeroed)
  float* msgA  = msg2 + (size_t)kN * kRD;        // 2*N*64  (zeroed)
  float* h1    = msgA + (size_t)2 * kN * kD;     // 2*N*64
  float* qb    = h1   + (size_t)2 * kN * kD;     // 2*N*64
  float* kb    = qb   + (size_t)2 * kN * kD;     // 2*N*64
  float* mean1 = kb   + (size_t)2 * kN * kD;     // 128
  float* inv1  = mean1 + 128;                    // 128
  float* mean2 = inv1 + 128;                     // 64
  float* inv2  = mean2 + 64;                     // 64
  int* selCols = (int*)(inv2 + 64);              // 2*N*64 ints
  int* selCnt  = selCols + (size_t)2 * kN * 64;  // 2*N ints

  // 264 MB output zero, chunked 8x so each fill dispatch's rocprof duration
  // sits below the compute kernels (R1-R8: one monolithic fill swamped the
  // top-5 table with ~155us artifact rows, hiding per-kernel compute data).
  // Total memset work identical to R1 (proven ~76us in-graph, size-linear).
  {
    const size_t totalB = (size_t)out_size * sizeof(float);
    const size_t chunkB = (totalB / 8) & ~(size_t)15;
    char* base = (char*)d_out;
    size_t off = 0;
    for (int c = 0; c < 7; ++c) {
      hipMemsetAsync(base + off, 0, chunkB, stream);
      off += chunkB;
    }
    hipMemsetAsync(base + off, 0, totalB - off, stream);
  }
  hipMemsetAsync(msg2, 0, (size_t)(kN * kRD + 2 * kN * kD) * sizeof(float), stream);

  k_scatter<<<kE / 4, 256, 0, stream>>>(x, ew, nin, nout, rel, msg2, msgA, nel);
  dim3 g2(kN / 4, 2);
  k_h1<<<g2, 256, 0, stream>>>(x, msgA, Wrel, Wself, bs, h1);
  k_bnstats<<<128, 256, 0, stream>>>(h1, mean1, inv1);
  k_qk<<<g2, 256, 0, stream>>>(h1, mean1, inv1, Wq, Wk, qb, kb);
  k_attn<<<(2 * kN) / 4, 256, 0, stream>>>(qb, kb, x, nel, msg2, selCols, selCnt);
  k_edgefix<<<kE / 4, 256, 0, stream>>>(x, ew, nin, nout, rel, selCols, selCnt, msg2);
  k_hpre<<<kN / 4, 256, 0, stream>>>(msg2, x, Wmsg, Wg, bg, hid);
  k_bnstats<<<64, 256, 0, stream>>>(hid, mean2, inv2);
  k_hfin<<<kN / 4, 256, 0, stream>>>(hid, mean2, inv2, gf);
}